// Round 1
// baseline (399.417 us; speedup 1.0000x reference)
//
#include <hip/hip_runtime.h>
#include <hip/hip_bf16.h>

#define B_    8
#define Q_    64
#define C_    512
#define HW_   256
#define E_    512
#define HATT_ 128
#define HMLP_ 512
#define NCLS_ 14
#define NLAB_ 64

__device__ __forceinline__ float gelu_exact(float x) {
    return 0.5f * x * (1.0f + erff(x * 0.7071067811865475f));
}
__device__ __forceinline__ float sigmoid_(float x) {
    return 1.0f / (1.0f + expf(-x));
}

// ---------------------------------------------------------------------------
// Kernel 1: per-label precompute.
//   GB[l][0:512]  = gamma_l = qt[l] @ W_film[:, :512]   + b_film[:512]
//   GB[l][512:]   = beta_l  = qt[l] @ W_film[:, 512:]   + b_film[512:]
//   Dl[l][h]      = beta_l @ W_att_h[:, h] + b_att_h[h]
// 64 blocks x 256 threads.
// ---------------------------------------------------------------------------
__global__ void precompute_gb(const float* __restrict__ qt,
                              const float* __restrict__ W_film,
                              const float* __restrict__ b_film,
                              const float* __restrict__ W_att_h,
                              const float* __restrict__ b_att_h,
                              float* __restrict__ GB,
                              float* __restrict__ Dl) {
    const int l = blockIdx.x;
    const int t = threadIdx.x;  // 256 threads
    __shared__ float qrow[E_];
    __shared__ float gbrow[2 * C_];

    qrow[t]       = qt[l * E_ + t];
    qrow[t + 256] = qt[l * E_ + t + 256];
    __syncthreads();

    #pragma unroll
    for (int k = 0; k < 4; ++k) {
        const int j = k * 256 + t;
        float acc = b_film[j];
        #pragma unroll 8
        for (int c = 0; c < E_; ++c) acc += qrow[c] * W_film[c * (2 * C_) + j];
        gbrow[j] = acc;
        GB[l * (2 * C_) + j] = acc;
    }
    __syncthreads();

    if (t < HATT_) {
        float acc = b_att_h[t];
        #pragma unroll 8
        for (int c = 0; c < C_; ++c) acc += gbrow[C_ + c] * W_att_h[c * HATT_ + t];
        Dl[l * HATT_ + t] = acc;
    }
}

// ---------------------------------------------------------------------------
// Kernel 2: fused head. One block per (b,q). 512 threads (8 waves).
// Phase A: hidden = f @ (gamma*W_att_h) + D, fused gelu + attn-dot epilogue.
// Phase B: p[c] = sum_n attn[n] * f[n,c];  pooled = (gamma*p + beta*A)/(A+eps)
// Phase C: z = gelu(pooled @ W_mlp1 + b1)
// Phase D: out = z @ W_mlp2 + b2
// ---------------------------------------------------------------------------
__global__ __launch_bounds__(512) void fused_head(
    const float* __restrict__ feature,
    const int*   __restrict__ label_ids,
    const float* __restrict__ W_att_h,
    const float* __restrict__ W_att_f,
    const float* __restrict__ b_att_f,
    const float* __restrict__ W_mlp1,
    const float* __restrict__ b_mlp1,
    const float* __restrict__ W_mlp2,
    const float* __restrict__ b_mlp2,
    const float* __restrict__ GB,
    const float* __restrict__ Dl,
    float* __restrict__ out) {

    const int t  = threadIdx.x;        // 0..511
    const int bq = blockIdx.x;         // 0..511
    const int b  = bq >> 6;
    const int l  = label_ids[bq];

    __shared__ float f_tile[32][HW_];     // 32 KB
    __shared__ float wg_tile[32][HATT_];  // 16 KB
    __shared__ float gamma_s[C_];
    __shared__ float beta_s[C_];
    __shared__ float d_s[HATT_];
    __shared__ float wf_s[HATT_];
    __shared__ float attn_s[HW_];
    __shared__ float p_s[C_];
    __shared__ float pooled_s[C_];
    __shared__ float z_s[HMLP_];
    __shared__ float red_s[32 * NCLS_];
    __shared__ float A_s;

    // stage per-label params (t covers 0..511)
    gamma_s[t] = GB[l * 1024 + t];
    beta_s[t]  = GB[l * 1024 + 512 + t];
    if (t < HATT_) {
        d_s[t]  = Dl[l * HATT_ + t];
        wf_s[t] = W_att_f[t];
    }
    __syncthreads();

    const int rg = t >> 3;   // 0..63 : rows 4rg..4rg+3 of hidden
    const int hg = t & 7;    // 0..7  : h-block of 16
    const int h0 = hg * 16;

    float acc[4][16];
    #pragma unroll
    for (int r = 0; r < 4; ++r)
        #pragma unroll
        for (int j = 0; j < 16; ++j) acc[r][j] = 0.f;

    const float* fb = feature + (size_t)b * C_ * HW_;  // f[b][c][n], c-major

    // ---------------- Phase A: GEMM 256x512x128 + fused epilogue ------------
    for (int c0 = 0; c0 < C_; c0 += 32) {
        #pragma unroll
        for (int k = 0; k < 4; ++k) {
            const int idx = k * 512 + t;
            const int row = idx >> 6, col = (idx & 63) * 4;
            *(float4*)&f_tile[row][col] =
                *(const float4*)&fb[(c0 + row) * HW_ + col];
        }
        #pragma unroll
        for (int k = 0; k < 2; ++k) {
            const int idx = k * 512 + t;
            const int row = idx >> 5, hh = (idx & 31) * 4;
            const float g = gamma_s[c0 + row];
            const float4 w = *(const float4*)&W_att_h[(c0 + row) * HATT_ + hh];
            float4 o; o.x = g * w.x; o.y = g * w.y; o.z = g * w.z; o.w = g * w.w;
            *(float4*)&wg_tile[row][hh] = o;
        }
        __syncthreads();

        for (int cc = 0; cc < 32; ++cc) {
            const float4 fv = *(const float4*)&f_tile[cc][rg * 4];
            const float4 w0 = *(const float4*)&wg_tile[cc][h0 + 0];
            const float4 w1 = *(const float4*)&wg_tile[cc][h0 + 4];
            const float4 w2 = *(const float4*)&wg_tile[cc][h0 + 8];
            const float4 w3 = *(const float4*)&wg_tile[cc][h0 + 12];
            const float fr[4] = {fv.x, fv.y, fv.z, fv.w};
            const float wv[16] = {w0.x, w0.y, w0.z, w0.w,
                                  w1.x, w1.y, w1.z, w1.w,
                                  w2.x, w2.y, w2.z, w2.w,
                                  w3.x, w3.y, w3.z, w3.w};
            #pragma unroll
            for (int r = 0; r < 4; ++r)
                #pragma unroll
                for (int j = 0; j < 16; ++j) acc[r][j] += fr[r] * wv[j];
        }
        __syncthreads();
    }

    // epilogue: gelu + dot with W_att_f, reduce across the 8 h-groups
    {
        const float baf = b_att_f[0];
        #pragma unroll
        for (int r = 0; r < 4; ++r) {
            float s = 0.f;
            #pragma unroll
            for (int j = 0; j < 16; ++j) {
                const int h = h0 + j;
                s += gelu_exact(acc[r][j] + d_s[h]) * wf_s[h];
            }
            #pragma unroll
            for (int m = 1; m < 8; m <<= 1) s += __shfl_xor(s, m);
            if (hg == 0) attn_s[rg * 4 + r] = sigmoid_(s + baf);
        }
    }
    __syncthreads();

    // A = sum_n attn[n]  (first wave)
    if (t < 64) {
        float a = attn_s[t] + attn_s[t + 64] + attn_s[t + 128] + attn_s[t + 192];
        #pragma unroll
        for (int m = 1; m < 64; m <<= 1) a += __shfl_xor(a, m);
        if (t == 0) A_s = a;
    }
    __syncthreads();

    // ---------------- Phase B: p[c] = sum_n attn[n] f[n,c] ------------------
    const int cr = t >> 4;   // 0..31
    const int ns = t & 15;   // 0..15
    for (int c0 = 0; c0 < C_; c0 += 32) {
        #pragma unroll
        for (int k = 0; k < 4; ++k) {
            const int idx = k * 512 + t;
            const int row = idx >> 6, col = (idx & 63) * 4;
            *(float4*)&f_tile[row][col] =
                *(const float4*)&fb[(c0 + row) * HW_ + col];
        }
        __syncthreads();
        float s = 0.f;
        #pragma unroll
        for (int k = 0; k < 16; ++k) {
            const int n = ns * 16 + k;
            s += attn_s[n] * f_tile[cr][n];
        }
        #pragma unroll
        for (int m = 1; m < 16; m <<= 1) s += __shfl_xor(s, m);
        if (ns == 0) p_s[c0 + cr] = s;
        __syncthreads();
    }

    {
        const float A = A_s;
        const float inv = 1.0f / (A + 1e-8f);
        pooled_s[t] = (gamma_s[t] * p_s[t] + beta_s[t] * A) * inv;
    }
    __syncthreads();

    // ---------------- Phase C: z = gelu(pooled @ W_mlp1 + b1) ---------------
    {
        float z = b_mlp1[t];
        #pragma unroll 8
        for (int c = 0; c < C_; ++c) z += pooled_s[c] * W_mlp1[c * HMLP_ + t];
        z_s[t] = gelu_exact(z);
    }
    __syncthreads();

    // ---------------- Phase D: out = z @ W_mlp2 + b2 ------------------------
    if (t < 448) {
        const int o = t % 14, seg = t / 14;
        float s = 0.f;
        #pragma unroll
        for (int k = 0; k < 16; ++k) {
            const int h = seg * 16 + k;
            s += z_s[h] * W_mlp2[h * NCLS_ + o];
        }
        red_s[seg * NCLS_ + o] = s;
    }
    __syncthreads();
    if (t < NCLS_) {
        float s = b_mlp2[t];
        #pragma unroll
        for (int seg = 0; seg < 32; ++seg) s += red_s[seg * NCLS_ + t];
        out[bq * NCLS_ + t] = s;
    }
}

// ---------------------------------------------------------------------------
extern "C" void kernel_launch(void* const* d_in, const int* in_sizes, int n_in,
                              void* d_out, int out_size, void* d_ws, size_t ws_size,
                              hipStream_t stream) {
    const float* feature   = (const float*)d_in[0];
    const int*   label_ids = (const int*)  d_in[1];
    const float* qt        = (const float*)d_in[2];
    const float* W_film    = (const float*)d_in[3];
    const float* b_film    = (const float*)d_in[4];
    const float* W_att_h   = (const float*)d_in[5];
    const float* b_att_h   = (const float*)d_in[6];
    const float* W_att_f   = (const float*)d_in[7];
    const float* b_att_f   = (const float*)d_in[8];
    const float* W_mlp1    = (const float*)d_in[9];
    const float* b_mlp1    = (const float*)d_in[10];
    const float* W_mlp2    = (const float*)d_in[11];
    const float* b_mlp2    = (const float*)d_in[12];
    float* out = (float*)d_out;

    float* GB = (float*)d_ws;            // 64 x 1024
    float* Dl = GB + NLAB_ * 2 * C_;     // 64 x 128  (total 294912 B of ws)

    hipLaunchKernelGGL(precompute_gb, dim3(NLAB_), dim3(256), 0, stream,
                       qt, W_film, b_film, W_att_h, b_att_h, GB, Dl);
    hipLaunchKernelGGL(fused_head, dim3(B_ * Q_), dim3(512), 0, stream,
                       feature, label_ids, W_att_h, W_att_f, b_att_f,
                       W_mlp1, b_mlp1, W_mlp2, b_mlp2, GB, Dl, out);
}

// Round 2
// 211.375 us; speedup vs baseline: 1.8896x; 1.8896x over previous
//
#include <hip/hip_runtime.h>
#include <hip/hip_bf16.h>

#define B_    8
#define Q_    64
#define C_    512
#define HW_   256
#define E_    512
#define HATT_ 128
#define HMLP_ 512
#define NCLS_ 14
#define NLAB_ 64

typedef unsigned short u16;
typedef unsigned int   u32;
typedef __attribute__((ext_vector_type(8))) short short8;   // 8 bf16 (4 VGPRs)
typedef __attribute__((ext_vector_type(4))) float f32x4;

// ws layout (bytes):
//   GB    @ 0        : 64x1024 f32  (gamma|beta per label)        256 KB
//   Dl    @ 262144   : 64x128  f32  (beta@W_att_h + b_att_h)       32 KB
//   W1bf  @ 294912   : 512x512 bf16                               512 KB
//   fT    @ 1048576  : 8x256x512 bf16   f transposed [b][n][c]      2 MB
//   WgT   @ 4194304  : 64 labels x 128KB swizzled bf16 B-operand    8 MB
#define WS_NEED 12582912

__device__ __forceinline__ float gelu_exact(float x) {
    return 0.5f * x * (1.0f + erff(x * 0.7071067811865475f));
}
__device__ __forceinline__ float sigmoid_(float x) {
    return 1.0f / (1.0f + expf(-x));
}
__device__ __forceinline__ u16 f2bf(float x) {              // RNE f32->bf16
    u32 u = __float_as_uint(x);
    u32 r = (u + 0x7fffu + ((u >> 16) & 1u)) >> 16;
    return (u16)r;
}
__device__ __forceinline__ float bf2f(u16 u) {
    return __uint_as_float(((u32)u) << 16);
}

// ---------------------------------------------------------------------------
// P1: per-label FiLM params. GB[l]=[gamma(512)|beta(512)], Dl[l][h]=beta@W+b.
// ---------------------------------------------------------------------------
__global__ void precompute_gb(const float* __restrict__ qt,
                              const float* __restrict__ W_film,
                              const float* __restrict__ b_film,
                              const float* __restrict__ W_att_h,
                              const float* __restrict__ b_att_h,
                              float* __restrict__ GB,
                              float* __restrict__ Dl) {
    const int l = blockIdx.x;
    const int t = threadIdx.x;  // 256
    __shared__ float qrow[E_];
    __shared__ float gbrow[2 * C_];

    qrow[t]       = qt[l * E_ + t];
    qrow[t + 256] = qt[l * E_ + t + 256];
    __syncthreads();

    #pragma unroll
    for (int k = 0; k < 4; ++k) {
        const int j = k * 256 + t;
        float acc = b_film[j];
        #pragma unroll 8
        for (int c = 0; c < E_; ++c) acc += qrow[c] * W_film[c * (2 * C_) + j];
        gbrow[j] = acc;
        GB[l * (2 * C_) + j] = acc;
    }
    __syncthreads();

    if (t < HATT_) {
        float acc = b_att_h[t];
        #pragma unroll 8
        for (int c = 0; c < C_; ++c) acc += gbrow[C_ + c] * W_att_h[c * HATT_ + t];
        Dl[l * HATT_ + t] = acc;
    }
}

// ---------------------------------------------------------------------------
// P2: per-label B-operand: WgT[l] holds bf16(gamma_l[c]*W_att_h[c][h]) in the
// exact byte layout the fused kernel's LDS wants:
//   chunk s (c-superstep, 32KB) -> byte  h*256 + ((ck*2) ^ ((h&7)<<4))
// XOR swizzle makes the 16-lane h-column ds_read_b128 hit all 8 granule slots
// (8-way = b128 floor) instead of 4 slots (16-way).
// ---------------------------------------------------------------------------
__global__ void prep_wg(const float* __restrict__ W_att_h,
                        const float* __restrict__ GB,
                        u16* __restrict__ WgT) {
    const int l = blockIdx.x;          // 64
    const int t = threadIdx.x;         // 256
    const int h = t & 127, chalf = t >> 7;
    char* basep = (char*)WgT + (size_t)l * 131072;
    for (int cblk = 0; cblk < 32; ++cblk) {
        const int c0 = chalf * 256 + cblk * 8;
        u16 pk[8];
        #pragma unroll
        for (int i = 0; i < 8; ++i) {
            const float g = GB[l * 1024 + c0 + i];
            pk[i] = f2bf(g * W_att_h[(c0 + i) * HATT_ + h]);
        }
        const int s = c0 >> 7, ck0 = c0 & 127;
        const int byteoff = s * 32768 + h * 256 + (((ck0 * 2)) ^ ((h & 7) << 4));
        *(uint4*)(basep + byteoff) = *(uint4*)pk;
    }
}

// ---------------------------------------------------------------------------
// P3: fT[b][n][c] = bf16(feature[b][c][n])  (64x64 LDS tile transpose)
// ---------------------------------------------------------------------------
__global__ void prep_ft(const float* __restrict__ feature, u16* __restrict__ fT) {
    const int bid = blockIdx.x;            // 256 = 8b x 8c x 4n
    const int b = bid >> 5, c0 = ((bid >> 2) & 7) * 64, n0 = (bid & 3) * 64;
    const int t = threadIdx.x;             // 256
    __shared__ float tile[64][65];
    const float* fb = feature + (size_t)b * C_ * HW_;

    const int cl = t >> 2, nq = t & 3;
    #pragma unroll
    for (int i = 0; i < 4; ++i) {
        float4 v = *(const float4*)&fb[(c0 + cl) * HW_ + n0 + nq * 16 + i * 4];
        tile[cl][nq * 16 + i * 4 + 0] = v.x;
        tile[cl][nq * 16 + i * 4 + 1] = v.y;
        tile[cl][nq * 16 + i * 4 + 2] = v.z;
        tile[cl][nq * 16 + i * 4 + 3] = v.w;
    }
    __syncthreads();
    const int nl = t >> 2, cq = t & 3;
    u16 pk[16];
    #pragma unroll
    for (int k = 0; k < 16; ++k) pk[k] = f2bf(tile[cq * 16 + k][nl]);
    u16* dst = fT + (size_t)(b * HW_ + n0 + nl) * C_ + c0 + cq * 16;
    *(uint4*)dst       = *(uint4*)pk;
    *(uint4*)(dst + 8) = *(uint4*)(pk + 8);
}

// ---------------------------------------------------------------------------
// P4: W1bf = bf16(W_mlp1)
// ---------------------------------------------------------------------------
__global__ void prep_w1(const float* __restrict__ W1, u16* __restrict__ W1bf) {
    const int i = (blockIdx.x * 256 + threadIdx.x) * 4;   // 256 blocks
    float4 v = *(const float4*)&W1[i];
    u16 pk[4] = {f2bf(v.x), f2bf(v.y), f2bf(v.z), f2bf(v.w)};
    *(uint2*)&W1bf[i] = *(uint2*)pk;
}

// ---------------------------------------------------------------------------
// Fused head, MFMA Phase A. One block per (b,q), 512 thr (8 waves, 4x2 grid).
// Per wave: 64(n) x 64(h) output = 4x4 frags of 16x16, K=512 in 4 supersteps
// of 128 (LDS B tile 32KB) x 4 k-steps of 32.
//  A-frags: direct global from fT (16-segment coalesced, L2-resident)
//  B-frags: swizzled ds_read_b128 from the staged WgT chunk
// ---------------------------------------------------------------------------
__global__ __launch_bounds__(512, 4) void fused_head_mfma(
    const int*   __restrict__ label_ids,
    const float* __restrict__ W_att_f,
    const float* __restrict__ b_att_f,
    const float* __restrict__ b_mlp1,
    const float* __restrict__ W_mlp2,
    const float* __restrict__ b_mlp2,
    const float* __restrict__ GB,
    const float* __restrict__ Dl,
    const u16*   __restrict__ fT,
    const u16*   __restrict__ WgT,
    const u16*   __restrict__ W1bf,
    float* __restrict__ out) {

    const int t  = threadIdx.x;
    const int bq = blockIdx.x;
    const int b  = bq >> 6;
    const int l  = label_ids[bq];

    __shared__ uint4 Bt4[2048];            // 32 KB B tile (swizzled bytes)
    __shared__ float d_s[HATT_];
    __shared__ float wf_s[HATT_];
    __shared__ float attn_part[2][HW_];
    __shared__ float attn_s[HW_];
    __shared__ float pooled_s[C_];
    __shared__ float z_s[HMLP_];
    __shared__ float red_s[32 * NCLS_];
    __shared__ float A_s;

    if (t < HATT_) {
        d_s[t]  = Dl[l * HATT_ + t];
        wf_s[t] = W_att_f[t];
    }

    const int lane = t & 63, w = t >> 6;
    const int wm = w >> 1, wc = w & 1;
    const int lr = lane & 15, lk = lane >> 4;
    const int n0w = wm * 64, hbase = wc * 64;

    const u16* fTb = fT + (size_t)b * HW_ * C_;
    const u16* wgl = WgT + (size_t)l * 65536;   // 131072 B / 2

    const f32x4 zero = {0.f, 0.f, 0.f, 0.f};
    f32x4 acc[4][4];
    #pragma unroll
    for (int mi = 0; mi < 4; ++mi)
        #pragma unroll
        for (int ni = 0; ni < 4; ++ni) acc[mi][ni] = zero;

    for (int s = 0; s < 4; ++s) {
        {   // stage 32KB chunk, global linear -> LDS linear
            const uint4* src = (const uint4*)(wgl + s * 16384);
            #pragma unroll
            for (int r = 0; r < 4; ++r) Bt4[r * 512 + t] = src[r * 512 + t];
        }
        __syncthreads();
        #pragma unroll
        for (int ks = 0; ks < 4; ++ks) {
            const int ck = ks * 32 + lk * 8;    // k within superstep
            short8 af[4], bf[4];
            #pragma unroll
            for (int mi = 0; mi < 4; ++mi)
                af[mi] = *(const short8*)(fTb + (size_t)(n0w + mi * 16 + lr) * C_
                                              + s * 128 + ck);
            #pragma unroll
            for (int ni = 0; ni < 4; ++ni) {
                const int h = hbase + ni * 16 + lr;
                const int byteoff = h * 256 + ((ck * 2) ^ ((h & 7) << 4));
                bf[ni] = *(const short8*)((const char*)Bt4 + byteoff);
            }
            #pragma unroll
            for (int mi = 0; mi < 4; ++mi)
                #pragma unroll
                for (int ni = 0; ni < 4; ++ni)
                    acc[mi][ni] = __builtin_amdgcn_mfma_f32_16x16x32_bf16(
                        af[mi], bf[ni], acc[mi][ni], 0, 0, 0);
        }
        __syncthreads();
    }

    // ---- epilogue: hidden = acc + D[h]; gelu; dot wf; per-n partial --------
    // C/D frag: col(h) = lane&15, row(n) = (lane>>4)*4 + j   [m89-verified]
    #pragma unroll
    for (int mi = 0; mi < 4; ++mi) {
        #pragma unroll
        for (int j = 0; j < 4; ++j) {
            float sum = 0.f;
            #pragma unroll
            for (int ni = 0; ni < 4; ++ni) {
                const int h = hbase + ni * 16 + lr;
                sum += gelu_exact(acc[mi][ni][j] + d_s[h]) * wf_s[h];
            }
            sum += __shfl_xor(sum, 1);
            sum += __shfl_xor(sum, 2);
            sum += __shfl_xor(sum, 4);
            sum += __shfl_xor(sum, 8);
            if (lr == 0) attn_part[wc][n0w + mi * 16 + lk * 4 + j] = sum;
        }
    }
    __syncthreads();
    if (t < HW_)
        attn_s[t] = sigmoid_(attn_part[0][t] + attn_part[1][t] + b_att_f[0]);
    __syncthreads();
    if (t < 64) {
        float a = attn_s[t] + attn_s[t + 64] + attn_s[t + 128] + attn_s[t + 192];
        #pragma unroll
        for (int m = 1; m < 64; m <<= 1) a += __shfl_xor(a, m);
        if (t == 0) A_s = a;
    }
    __syncthreads();

    // ---- Phase B: p[c]=sum_n attn[n] fT[n][c]; thread t owns c=t -----------
    {
        float p = 0.f;
        const u16* fcol = fTb + t;
        #pragma unroll 8
        for (int n = 0; n < HW_; ++n) p += attn_s[n] * bf2f(fcol[n * C_]);
        const float A = A_s, inv = 1.0f / (A + 1e-8f);
        const float g  = GB[l * 1024 + t];
        const float be = GB[l * 1024 + 512 + t];
        pooled_s[t] = (g * p + be * A) * inv;
    }
    __syncthreads();

    // ---- Phase C: z = gelu(pooled @ W1 + b1) -------------------------------
    {
        float z = b_mlp1[t];
        const u16* w1c = W1bf + t;
        #pragma unroll 8
        for (int c = 0; c < C_; ++c) z += pooled_s[c] * bf2f(w1c[c * HMLP_]);
        z_s[t] = gelu_exact(z);
    }
    __syncthreads();

    // ---- Phase D: out = z @ W_mlp2 + b2 ------------------------------------
    if (t < 448) {
        const int o = t % 14, seg = t / 14;
        float s = 0.f;
        #pragma unroll
        for (int k = 0; k < 16; ++k) {
            const int h = seg * 16 + k;
            s += z_s[h] * W_mlp2[h * NCLS_ + o];
        }
        red_s[seg * NCLS_ + o] = s;
    }
    __syncthreads();
    if (t < NCLS_) {
        float s = b_mlp2[t];
        #pragma unroll
        for (int seg = 0; seg < 32; ++seg) s += red_s[seg * NCLS_ + t];
        out[bq * NCLS_ + t] = s;
    }
}

// ---------------------------------------------------------------------------
// Fallback (R1 kernel) if ws_size < WS_NEED — fp32 VALU path, 295KB ws.
// ---------------------------------------------------------------------------
__global__ __launch_bounds__(512) void fused_head_fb(
    const float* __restrict__ feature, const int* __restrict__ label_ids,
    const float* __restrict__ W_att_h, const float* __restrict__ W_att_f,
    const float* __restrict__ b_att_f, const float* __restrict__ W_mlp1,
    const float* __restrict__ b_mlp1, const float* __restrict__ W_mlp2,
    const float* __restrict__ b_mlp2, const float* __restrict__ GB,
    const float* __restrict__ Dl, float* __restrict__ out) {
    const int t = threadIdx.x, bq = blockIdx.x, b = bq >> 6, l = label_ids[bq];
    __shared__ float f_tile[32][HW_];
    __shared__ float wg_tile[32][HATT_];
    __shared__ float gamma_s[C_], beta_s[C_], d_s[HATT_], wf_s[HATT_];
    __shared__ float attn_s[HW_], p_s[C_], pooled_s[C_], z_s[HMLP_];
    __shared__ float red_s[32 * NCLS_];
    __shared__ float A_s;
    gamma_s[t] = GB[l * 1024 + t];
    beta_s[t]  = GB[l * 1024 + 512 + t];
    if (t < HATT_) { d_s[t] = Dl[l * HATT_ + t]; wf_s[t] = W_att_f[t]; }
    __syncthreads();
    const int rg = t >> 3, hg = t & 7, h0 = hg * 16;
    float acc[4][16];
    #pragma unroll
    for (int r = 0; r < 4; ++r)
        #pragma unroll
        for (int j = 0; j < 16; ++j) acc[r][j] = 0.f;
    const float* fb = feature + (size_t)b * C_ * HW_;
    for (int c0 = 0; c0 < C_; c0 += 32) {
        #pragma unroll
        for (int k = 0; k < 4; ++k) {
            const int idx = k * 512 + t, row = idx >> 6, col = (idx & 63) * 4;
            *(float4*)&f_tile[row][col] = *(const float4*)&fb[(c0 + row) * HW_ + col];
        }
        #pragma unroll
        for (int k = 0; k < 2; ++k) {
            const int idx = k * 512 + t, row = idx >> 5, hh = (idx & 31) * 4;
            const float g = gamma_s[c0 + row];
            const float4 wv = *(const float4*)&W_att_h[(c0 + row) * HATT_ + hh];
            float4 o; o.x = g * wv.x; o.y = g * wv.y; o.z = g * wv.z; o.w = g * wv.w;
            *(float4*)&wg_tile[row][hh] = o;
        }
        __syncthreads();
        for (int cc = 0; cc < 32; ++cc) {
            const float4 fv = *(const float4*)&f_tile[cc][rg * 4];
            const float4 w0 = *(const float4*)&wg_tile[cc][h0 + 0];
            const float4 w1 = *(const float4*)&wg_tile[cc][h0 + 4];
            const float4 w2 = *(const float4*)&wg_tile[cc][h0 + 8];
            const float4 w3 = *(const float4*)&wg_tile[cc][h0 + 12];
            const float fr[4] = {fv.x, fv.y, fv.z, fv.w};
            const float wvv[16] = {w0.x, w0.y, w0.z, w0.w, w1.x, w1.y, w1.z, w1.w,
                                   w2.x, w2.y, w2.z, w2.w, w3.x, w3.y, w3.z, w3.w};
            #pragma unroll
            for (int r = 0; r < 4; ++r)
                #pragma unroll
                for (int j = 0; j < 16; ++j) acc[r][j] += fr[r] * wvv[j];
        }
        __syncthreads();
    }
    {
        const float baf = b_att_f[0];
        #pragma unroll
        for (int r = 0; r < 4; ++r) {
            float s = 0.f;
            #pragma unroll
            for (int j = 0; j < 16; ++j) {
                const int h = h0 + j;
                s += gelu_exact(acc[r][j] + d_s[h]) * wf_s[h];
            }
            #pragma unroll
            for (int m = 1; m < 8; m <<= 1) s += __shfl_xor(s, m);
            if (hg == 0) attn_s[rg * 4 + r] = sigmoid_(s + baf);
        }
    }
    __syncthreads();
    if (t < 64) {
        float a = attn_s[t] + attn_s[t + 64] + attn_s[t + 128] + attn_s[t + 192];
        #pragma unroll
        for (int m = 1; m < 64; m <<= 1) a += __shfl_xor(a, m);
        if (t == 0) A_s = a;
    }
    __syncthreads();
    const int cr = t >> 4, ns = t & 15;
    for (int c0 = 0; c0 < C_; c0 += 32) {
        #pragma unroll
        for (int k = 0; k < 4; ++k) {
            const int idx = k * 512 + t, row = idx >> 6, col = (idx & 63) * 4;
            *(float4*)&f_tile[row][col] = *(const float4*)&fb[(c0 + row) * HW_ + col];
        }
        __syncthreads();
        float s = 0.f;
        #pragma unroll
        for (int k = 0; k < 16; ++k) { const int n = ns * 16 + k; s += attn_s[n] * f_tile[cr][n]; }
        #pragma unroll
        for (int m = 1; m < 16; m <<= 1) s += __shfl_xor(s, m);
        if (ns == 0) p_s[c0 + cr] = s;
        __syncthreads();
    }
    {
        const float A = A_s, inv = 1.0f / (A + 1e-8f);
        pooled_s[t] = (gamma_s[t] * p_s[t] + beta_s[t] * A) * inv;
    }
    __syncthreads();
    {
        float z = b_mlp1[t];
        #pragma unroll 8
        for (int c = 0; c < C_; ++c) z += pooled_s[c] * W_mlp1[c * HMLP_ + t];
        z_s[t] = gelu_exact(z);
    }
    __syncthreads();
    if (t < 448) {
        const int o = t % 14, seg = t / 14;
        float s = 0.f;
        #pragma unroll
        for (int k = 0; k < 16; ++k) { const int h = seg * 16 + k; s += z_s[h] * W_mlp2[h * NCLS_ + o]; }
        red_s[seg * NCLS_ + o] = s;
    }
    __syncthreads();
    if (t < NCLS_) {
        float s = b_mlp2[t];
        #pragma unroll
        for (int seg = 0; seg < 32; ++seg) s += red_s[seg * NCLS_ + t];
        out[bq * NCLS_ + t] = s;
    }
}

// ---------------------------------------------------------------------------
extern "C" void kernel_launch(void* const* d_in, const int* in_sizes, int n_in,
                              void* d_out, int out_size, void* d_ws, size_t ws_size,
                              hipStream_t stream) {
    const float* feature   = (const float*)d_in[0];
    const int*   label_ids = (const int*)  d_in[1];
    const float* qt        = (const float*)d_in[2];
    const float* W_film    = (const float*)d_in[3];
    const float* b_film    = (const float*)d_in[4];
    const float* W_att_h   = (const float*)d_in[5];
    const float* b_att_h   = (const float*)d_in[6];
    const float* W_att_f   = (const float*)d_in[7];
    const float* b_att_f   = (const float*)d_in[8];
    const float* W_mlp1    = (const float*)d_in[9];
    const float* b_mlp1    = (const float*)d_in[10];
    const float* W_mlp2    = (const float*)d_in[11];
    const float* b_mlp2    = (const float*)d_in[12];
    float* out = (float*)d_out;

    char* wsb  = (char*)d_ws;
    float* GB  = (float*)wsb;                  // 256 KB
    float* Dl  = (float*)(wsb + 262144);       //  32 KB
    u16* W1bf  = (u16*)(wsb + 294912);         // 512 KB
    u16* fTp   = (u16*)(wsb + 1048576);        //   2 MB
    u16* WgT   = (u16*)(wsb + 4194304);        //   8 MB

    hipLaunchKernelGGL(precompute_gb, dim3(NLAB_), dim3(256), 0, stream,
                       qt, W_film, b_film, W_att_h, b_att_h, GB, Dl);

    if (ws_size >= (size_t)WS_NEED) {
        hipLaunchKernelGGL(prep_wg, dim3(NLAB_), dim3(256), 0, stream, W_att_h, GB, WgT);
        hipLaunchKernelGGL(prep_ft, dim3(256), dim3(256), 0, stream, feature, fTp);
        hipLaunchKernelGGL(prep_w1, dim3(256), dim3(256), 0, stream, W_mlp1, W1bf);
        hipLaunchKernelGGL(fused_head_mfma, dim3(B_ * Q_), dim3(512), 0, stream,
                           label_ids, W_att_f, b_att_f, b_mlp1, W_mlp2, b_mlp2,
                           GB, Dl, fTp, WgT, W1bf, out);
    } else {
        hipLaunchKernelGGL(fused_head_fb, dim3(B_ * Q_), dim3(512), 0, stream,
                           feature, label_ids, W_att_h, W_att_f, b_att_f,
                           W_mlp1, b_mlp1, W_mlp2, b_mlp2, GB, Dl, out);
    }
}

// Round 3
// 80.961 us; speedup vs baseline: 4.9335x; 2.6108x over previous
//
#include <hip/hip_runtime.h>
#include <hip/hip_bf16.h>

#define B_    8
#define Q_    64
#define C_    512
#define HW_   256
#define E_    512
#define HATT_ 128
#define HMLP_ 512
#define NCLS_ 14
#define NLAB_ 64

typedef unsigned short u16;
typedef unsigned int   u32;
typedef __attribute__((ext_vector_type(8))) short short8;   // 8 bf16
typedef __attribute__((ext_vector_type(4))) float f32x4;

// ws layout (bytes):
//   GBp  @ 0       : 256x1024 f32 GB partials                 1 MB
//   GB   @ 1048576 : 64x1024 f32 (gamma|beta per label)     256 KB
//   Dl   @ 1310720 : 64x128  f32 (beta@W_att_h + b_att_h)    32 KB
//   WT   @ 1343488 : 128x512 bf16 W_att_h transposed [h][c] 128 KB
//   W1bf @ 1474560 : 512x512 bf16 W_mlp1                    512 KB
//   fT   @ 1998848 : 8x256x512 bf16 feature^T [b][n][c]       2 MB
// total 4096000 B  (< previously-proven-available 12.6 MB)

__device__ __forceinline__ float gelu_exact(float x) {
    return 0.5f * x * (1.0f + erff(x * 0.7071067811865475f));
}
__device__ __forceinline__ float sigmoid_(float x) {
    return 1.0f / (1.0f + expf(-x));
}
__device__ __forceinline__ u16 f2bf(float x) {              // RNE f32->bf16
    u32 u = __float_as_uint(x);
    u32 r = (u + 0x7fffu + ((u >> 16) & 1u)) >> 16;
    return (u16)r;
}
__device__ __forceinline__ u32 cvt_pk_bf16(float lo, float hi) {
    u32 r;
    asm("v_cvt_pk_bf16_f32 %0, %1, %2" : "=v"(r) : "v"(lo), "v"(hi));
    return r;   // lo -> D[15:0], hi -> D[31:16]
}

// ---------------------------------------------------------------------------
// P0 (merged label-independent preps + GB partial GEMM), 592 blocks x 256 thr:
//  [0,256)   K1a: GBp[(l,cq)][j] = sum_{c in cq-slice} qt[l][c] W_film[c][j]
//  [256,272) WT transpose: WT[h][c] = bf16(W_att_h[c][h])
//  [272,528) fT transpose: fT[b][n][c] = bf16(feature[b][c][n])
//  [528,592) W1bf = bf16(W_mlp1)
// ---------------------------------------------------------------------------
__global__ __launch_bounds__(256) void prep_misc(
    const float* __restrict__ qt, const float* __restrict__ W_film,
    const float* __restrict__ W_att_h, const float* __restrict__ feature,
    const float* __restrict__ W_mlp1,
    float* __restrict__ GBp, u16* __restrict__ WT,
    u16* __restrict__ W1bf, u16* __restrict__ fT) {

    __shared__ __align__(16) char sm[16640];
    const int bid = blockIdx.x, t = threadIdx.x;

    if (bid < 256) {                       // ---- GB partials
        float* qrow = (float*)sm;          // 128 floats
        const int l = bid >> 2, cq = bid & 3;
        if (t < 128) qrow[t] = qt[l * E_ + cq * 128 + t];
        __syncthreads();
        const float* wp = W_film + (size_t)(cq * 128) * 1024 + t * 4;
        f32x4 a = {0.f, 0.f, 0.f, 0.f};
        #pragma unroll 8
        for (int c = 0; c < 128; ++c) {
            const float4 w = *(const float4*)(wp + (size_t)c * 1024);
            const float q = qrow[c];
            a.x += q * w.x; a.y += q * w.y; a.z += q * w.z; a.w += q * w.w;
        }
        *(f32x4*)&GBp[(size_t)bid * 1024 + t * 4] = a;
    } else if (bid < 272) {                // ---- WT transpose (bf16)
        float (*tile)[129] = (float(*)[129])sm;     // 32 x 129
        const int c0 = (bid - 256) * 32;
        const int cl = t >> 3, hq = t & 7;
        #pragma unroll
        for (int i = 0; i < 4; ++i) {
            const int h = hq * 16 + i * 4;
            *(float4*)&tile[cl][h] = *(const float4*)&W_att_h[(c0 + cl) * HATT_ + h];
        }
        __syncthreads();
        const int h = t >> 1, half = t & 1;
        u16 pk[16];
        #pragma unroll
        for (int i = 0; i < 16; ++i) pk[i] = f2bf(tile[half * 16 + i][h]);
        u16* dst = WT + (size_t)h * C_ + c0 + half * 16;
        *(uint4*)dst       = *(uint4*)pk;
        *(uint4*)(dst + 8) = *(uint4*)(pk + 8);
    } else if (bid < 528) {                // ---- fT transpose
        float (*tile)[65] = (float(*)[65])sm;       // 64 x 65
        const int bb = bid - 272;
        const int b = bb >> 5, c0 = ((bb >> 2) & 7) * 64, n0 = (bb & 3) * 64;
        const float* fb = feature + (size_t)b * C_ * HW_;
        const int cl = t >> 2, nq = t & 3;
        #pragma unroll
        for (int i = 0; i < 4; ++i) {
            float4 v = *(const float4*)&fb[(c0 + cl) * HW_ + n0 + nq * 16 + i * 4];
            tile[cl][nq * 16 + i * 4 + 0] = v.x;
            tile[cl][nq * 16 + i * 4 + 1] = v.y;
            tile[cl][nq * 16 + i * 4 + 2] = v.z;
            tile[cl][nq * 16 + i * 4 + 3] = v.w;
        }
        __syncthreads();
        const int nl = t >> 2, cqq = t & 3;
        u16 pk[16];
        #pragma unroll
        for (int k = 0; k < 16; ++k) pk[k] = f2bf(tile[cqq * 16 + k][nl]);
        u16* dst = fT + (size_t)(b * HW_ + n0 + nl) * C_ + c0 + cqq * 16;
        *(uint4*)dst       = *(uint4*)pk;
        *(uint4*)(dst + 8) = *(uint4*)(pk + 8);
    } else {                               // ---- W1 -> bf16
        const int b2 = bid - 528;
        #pragma unroll
        for (int k = 0; k < 2; ++k) {
            const int idx = (b2 * 512 + k * 256 + t) * 8;
            float4 v0 = *(const float4*)&W_mlp1[idx];
            float4 v1 = *(const float4*)&W_mlp1[idx + 4];
            u16 pk[8] = {f2bf(v0.x), f2bf(v0.y), f2bf(v0.z), f2bf(v0.w),
                         f2bf(v1.x), f2bf(v1.y), f2bf(v1.z), f2bf(v1.w)};
            *(uint4*)&W1bf[idx] = *(uint4*)pk;
        }
    }
}

// ---------------------------------------------------------------------------
// P1: GB reduce (+b_film) and Dl = beta @ W_att_h + b_att_h.  64 blk x 512 thr
// ---------------------------------------------------------------------------
__global__ __launch_bounds__(512) void prep_gb2(
    const float* __restrict__ b_film, const float* __restrict__ W_att_h,
    const float* __restrict__ b_att_h, const float* __restrict__ GBp,
    float* __restrict__ GB, float* __restrict__ Dl) {
    __shared__ float beta_sh[C_];
    __shared__ float dred[4 * HATT_];
    const int l = blockIdx.x, t = threadIdx.x;
    const float* P = GBp + (size_t)l * 4096;
    float s0 = b_film[t]       + P[t]       + P[1024 + t]       + P[2048 + t]       + P[3072 + t];
    float s1 = b_film[t + 512] + P[t + 512] + P[1024 + t + 512] + P[2048 + t + 512] + P[3072 + t + 512];
    GB[l * 1024 + t]       = s0;
    GB[l * 1024 + 512 + t] = s1;
    beta_sh[t] = s1;
    __syncthreads();
    const int h = t & 127, cp = t >> 7;
    float a = 0.f;
    #pragma unroll 8
    for (int c = cp * 128; c < cp * 128 + 128; ++c)
        a += beta_sh[c] * W_att_h[c * HATT_ + h];
    dred[cp * HATT_ + h] = a;
    __syncthreads();
    if (t < HATT_)
        Dl[l * HATT_ + t] = b_att_h[t] + dred[t] + dred[128 + t] + dred[256 + t] + dred[384 + t];
}

// ---------------------------------------------------------------------------
// Fused head. 512 blocks (XCD-swizzled: each XCD owns one b) x 512 threads.
// Phase A: hidden = fT @ (gamma*WT^T) via MFMA; B staged dbl-buffered into LDS
//          with on-the-fly gamma scaling (WT is label-independent, L2-hot).
// Epilogue -> attn; Phase B/C with K-split + LDS reduce; Phase D tiny GEMM.
// All post-A scratch aliases the dead 64KB B-buffer.
// ---------------------------------------------------------------------------
__global__ __launch_bounds__(512, 4) void fused_head(
    const int*   __restrict__ label_ids,
    const float* __restrict__ W_att_f, const float* __restrict__ b_att_f,
    const float* __restrict__ b_mlp1,  const float* __restrict__ W_mlp2,
    const float* __restrict__ b_mlp2,  const float* __restrict__ GB,
    const float* __restrict__ Dl,      const u16* __restrict__ WT,
    const u16*   __restrict__ fT,      const u16* __restrict__ W1bf,
    float* __restrict__ out) {

    __shared__ __align__(16) char big[65536];   // B dbuf; post-A scratch union
    __shared__ float gamma_s[C_];
    __shared__ float beta_s[C_];
    __shared__ float d_s[HATT_];
    __shared__ float wf_s[HATT_];

    const int t = threadIdx.x;
    const int bq = (blockIdx.x & 7) * 64 + (blockIdx.x >> 3);  // XCD: one b each
    const int b = bq >> 6, l = label_ids[bq];

    gamma_s[t] = GB[l * 1024 + t];
    beta_s[t]  = GB[l * 1024 + 512 + t];
    if (t < HATT_) { d_s[t] = Dl[l * HATT_ + t]; wf_s[t] = W_att_f[t]; }

    // staging geometry: chunk k: gid=k*512+t -> LDS byte gid*16 holds 8 bf16
    // of (h = gid>>4, c = s*128 + ck0..ck0+8), ck0 = ((gid&15)^(h&7))*8.
    const int srow = t >> 4;                       // h = k*32 + srow
    const int ck0  = ((t & 15) ^ (srow & 7)) * 8;  // k-independent

    const int lane = t & 63, w = t >> 6;
    const int wm = w >> 1, wc = w & 1;
    const int lr = lane & 15, lk = lane >> 4;
    const int n0w = wm * 64, hbase = wc * 64;
    const u16* fTb = fT + (size_t)b * HW_ * C_;

    const f32x4 zero = {0.f, 0.f, 0.f, 0.f};
    f32x4 acc[4][4];
    #pragma unroll
    for (int mi = 0; mi < 4; ++mi)
        #pragma unroll
        for (int ni = 0; ni < 4; ++ni) acc[mi][ni] = zero;

    uint4 wv[4];
    #define STAGE_LOAD(s_)                                                    \
        _Pragma("unroll")                                                     \
        for (int k = 0; k < 4; ++k)                                           \
            wv[k] = *(const uint4*)(WT + (size_t)(k * 32 + srow) * C_ +       \
                                    (s_) * 128 + ck0);
    #define STAGE_WRITE(buf_, s_) {                                           \
        const float4 g0 = *(const float4*)&gamma_s[(s_) * 128 + ck0];         \
        const float4 g1 = *(const float4*)&gamma_s[(s_) * 128 + ck0 + 4];     \
        _Pragma("unroll")                                                     \
        for (int k = 0; k < 4; ++k) {                                         \
            uint4 r;                                                          \
            r.x = cvt_pk_bf16(__uint_as_float(wv[k].x << 16) * g0.x,          \
                              __uint_as_float(wv[k].x & 0xffff0000u) * g0.y); \
            r.y = cvt_pk_bf16(__uint_as_float(wv[k].y << 16) * g0.z,          \
                              __uint_as_float(wv[k].y & 0xffff0000u) * g0.w); \
            r.z = cvt_pk_bf16(__uint_as_float(wv[k].z << 16) * g1.x,          \
                              __uint_as_float(wv[k].z & 0xffff0000u) * g1.y); \
            r.w = cvt_pk_bf16(__uint_as_float(wv[k].w << 16) * g1.z,          \
                              __uint_as_float(wv[k].w & 0xffff0000u) * g1.w); \
            *(uint4*)(big + (buf_) * 32768 + (k * 512 + t) * 16) = r;         \
        } }

    __syncthreads();                 // gamma_s ready
    STAGE_LOAD(0); STAGE_WRITE(0, 0);
    __syncthreads();

    for (int s = 0; s < 4; ++s) {
        const int buf = s & 1;
        if (s < 3) STAGE_LOAD(s + 1);
        #pragma unroll
        for (int ks = 0; ks < 4; ++ks) {
            const int ck = ks * 32 + lk * 8;
            short8 af[4], bfr[4];
            #pragma unroll
            for (int mi = 0; mi < 4; ++mi)
                af[mi] = *(const short8*)(fTb + (size_t)(n0w + mi * 16 + lr) * C_
                                              + s * 128 + ck);
            #pragma unroll
            for (int ni = 0; ni < 4; ++ni) {
                const int h = hbase + ni * 16 + lr;
                bfr[ni] = *(const short8*)(big + buf * 32768 + h * 256
                                               + ((ck * 2) ^ ((h & 7) << 4)));
            }
            #pragma unroll
            for (int mi = 0; mi < 4; ++mi)
                #pragma unroll
                for (int ni = 0; ni < 4; ++ni)
                    acc[mi][ni] = __builtin_amdgcn_mfma_f32_16x16x32_bf16(
                        af[mi], bfr[ni], acc[mi][ni], 0, 0, 0);
        }
        if (s < 3) STAGE_WRITE(buf ^ 1, s + 1);
        __syncthreads();
    }

    // post-A scratch aliased into big (all uses are behind barriers)
    float* attn_part = (float*)(big);             //  512 f32
    float* attn_s    = (float*)(big + 2048);      //  256 f32
    float* A_sp      = (float*)(big + 3072);      //    1 f32
    float* pBred     = (float*)(big + 4096);      // 4x128 f32x4 (8 KB)
    float* pooled_s  = (float*)(big + 12288);     //  512 f32
    float* zred      = (float*)(big + 14336);     // 8x512 f32 (16 KB)
    float* z_s       = (float*)(big + 30720);     //  512 f32
    float* red_s     = (float*)(big + 32768);     //  448 f32

    // ---- epilogue: gelu(hidden+D) . wf  -> attn  (C/D: col=lr, row=lk*4+j)
    #pragma unroll
    for (int mi = 0; mi < 4; ++mi) {
        #pragma unroll
        for (int j = 0; j < 4; ++j) {
            float sum = 0.f;
            #pragma unroll
            for (int ni = 0; ni < 4; ++ni) {
                const int h = hbase + ni * 16 + lr;
                sum += gelu_exact(acc[mi][ni][j] + d_s[h]) * wf_s[h];
            }
            sum += __shfl_xor(sum, 1);
            sum += __shfl_xor(sum, 2);
            sum += __shfl_xor(sum, 4);
            sum += __shfl_xor(sum, 8);
            if (lr == 0) attn_part[wc * 256 + n0w + mi * 16 + lk * 4 + j] = sum;
        }
    }
    __syncthreads();
    if (t < HW_)
        attn_s[t] = sigmoid_(attn_part[t] + attn_part[256 + t] + b_att_f[0]);
    __syncthreads();
    if (t < 64) {
        float a = attn_s[t] + attn_s[t + 64] + attn_s[t + 128] + attn_s[t + 192];
        #pragma unroll
        for (int m = 1; m < 64; m <<= 1) a += __shfl_xor(a, m);
        if (t == 0) *A_sp = a;
    }
    __syncthreads();

    // ---- Phase B: p[c] = sum_n attn[n] fT[n][c]; 128 c-quads x 4 n-groups
    {
        const int cq = t & 127, ng = t >> 7;
        f32x4 p = zero;
        const u16* fp = fTb + cq * 4;
        #pragma unroll 8
        for (int n = ng * 64; n < ng * 64 + 64; ++n) {
            const uint2 v = *(const uint2*)(fp + (size_t)n * C_);
            const float a = attn_s[n];
            p.x += a * __uint_as_float(v.x << 16);
            p.y += a * __uint_as_float(v.x & 0xffff0000u);
            p.z += a * __uint_as_float(v.y << 16);
            p.w += a * __uint_as_float(v.y & 0xffff0000u);
        }
        *(f32x4*)&pBred[(ng * 128 + cq) * 4] = p;
    }
    __syncthreads();
    if (t < 128) {
        f32x4 q = zero;
        #pragma unroll
        for (int g = 0; g < 4; ++g) {
            const f32x4 v = *(const f32x4*)&pBred[(g * 128 + t) * 4];
            q.x += v.x; q.y += v.y; q.z += v.z; q.w += v.w;
        }
        const float A = *A_sp, inv = 1.0f / (A + 1e-8f);
        #pragma unroll
        for (int i = 0; i < 4; ++i) {
            const int c = t * 4 + i;
            pooled_s[c] = (gamma_s[c] * q[i] + beta_s[c] * A) * inv;
        }
    }
    __syncthreads();

    // ---- Phase C: z = gelu(pooled @ W1 + b1); 64 h-octs x 8 c-groups
    {
        const int hq = t & 63, cg = t >> 6;
        float z[8] = {0.f, 0.f, 0.f, 0.f, 0.f, 0.f, 0.f, 0.f};
        const u16* wp1 = W1bf + hq * 8;
        #pragma unroll 8
        for (int c = cg * 64; c < cg * 64 + 64; ++c) {
            const uint4 v = *(const uint4*)(wp1 + (size_t)c * HMLP_);
            const float pc = pooled_s[c];
            z[0] += pc * __uint_as_float(v.x << 16);
            z[1] += pc * __uint_as_float(v.x & 0xffff0000u);
            z[2] += pc * __uint_as_float(v.y << 16);
            z[3] += pc * __uint_as_float(v.y & 0xffff0000u);
            z[4] += pc * __uint_as_float(v.z << 16);
            z[5] += pc * __uint_as_float(v.z & 0xffff0000u);
            z[6] += pc * __uint_as_float(v.w << 16);
            z[7] += pc * __uint_as_float(v.w & 0xffff0000u);
        }
        float* zr = &zred[cg * 512 + hq * 8];
        *(f32x4*)zr       = {z[0], z[1], z[2], z[3]};
        *(f32x4*)(zr + 4) = {z[4], z[5], z[6], z[7]};
    }
    __syncthreads();
    {
        float zz = b_mlp1[t];
        #pragma unroll
        for (int g = 0; g < 8; ++g) zz += zred[g * 512 + t];
        z_s[t] = gelu_exact(zz);
    }
    __syncthreads();

    // ---- Phase D: out = z @ W_mlp2 + b2
    if (t < 448) {
        const int o = t % 14, seg = t / 14;
        float s = 0.f;
        #pragma unroll
        for (int k = 0; k < 16; ++k) {
            const int h = seg * 16 + k;
            s += z_s[h] * W_mlp2[h * NCLS_ + o];
        }
        red_s[seg * NCLS_ + o] = s;
    }
    __syncthreads();
    if (t < NCLS_) {
        float s = b_mlp2[t];
        #pragma unroll
        for (int seg = 0; seg < 32; ++seg) s += red_s[seg * NCLS_ + t];
        out[bq * NCLS_ + t] = s;
    }
}

// ---------------------------------------------------------------------------
extern "C" void kernel_launch(void* const* d_in, const int* in_sizes, int n_in,
                              void* d_out, int out_size, void* d_ws, size_t ws_size,
                              hipStream_t stream) {
    const float* feature   = (const float*)d_in[0];
    const int*   label_ids = (const int*)  d_in[1];
    const float* qt        = (const float*)d_in[2];
    const float* W_film    = (const float*)d_in[3];
    const float* b_film    = (const float*)d_in[4];
    const float* W_att_h   = (const float*)d_in[5];
    const float* b_att_h   = (const float*)d_in[6];
    const float* W_att_f   = (const float*)d_in[7];
    const float* b_att_f   = (const float*)d_in[8];
    const float* W_mlp1    = (const float*)d_in[9];
    const float* b_mlp1    = (const float*)d_in[10];
    const float* W_mlp2    = (const float*)d_in[11];
    const float* b_mlp2    = (const float*)d_in[12];
    float* out = (float*)d_out;

    char* wsb  = (char*)d_ws;
    float* GBp = (float*)wsb;                   //   1 MB
    float* GB  = (float*)(wsb + 1048576);       // 256 KB
    float* Dl  = (float*)(wsb + 1310720);       //  32 KB
    u16*   WT  = (u16*)  (wsb + 1343488);       // 128 KB
    u16*   W1bf= (u16*)  (wsb + 1474560);       // 512 KB
    u16*   fTp = (u16*)  (wsb + 1998848);       //   2 MB

    hipLaunchKernelGGL(prep_misc, dim3(592), dim3(256), 0, stream,
                       qt, W_film, W_att_h, feature, W_mlp1, GBp, WT, W1bf, fTp);
    hipLaunchKernelGGL(prep_gb2, dim3(NLAB_), dim3(512), 0, stream,
                       b_film, W_att_h, b_att_h, GBp, GB, Dl);
    hipLaunchKernelGGL(fused_head, dim3(B_ * Q_), dim3(512), 0, stream,
                       label_ids, W_att_f, b_att_f, b_mlp1, W_mlp2, b_mlp2,
                       GB, Dl, WT, fTp, W1bf, out);
}